// Round 8
// baseline (557.848 us; speedup 1.0000x reference)
//
#include <hip/hip_runtime.h>
#include <hip/hip_bf16.h>

#define KK 32
#define INF 128
#define DD 64
#define OW 95   // 31 (row) + 64 (col)

typedef __attribute__((ext_vector_type(8))) short s8v;    // 8 bf16 (4 VGPR)
typedef __attribute__((ext_vector_type(4))) float f32x4;  // MFMA accumulator

__device__ __forceinline__ float bf2f(unsigned short u) {
    union { unsigned int i; float f; } cv; cv.i = (unsigned int)u << 16; return cv.f;
}
__device__ __forceinline__ unsigned short f2bf(float f) {
    __hip_bfloat16 hh = __float2bfloat16(f);
    return *reinterpret_cast<unsigned short*>(&hh);
}
__device__ __forceinline__ s8v pack8(float4 a, float4 b) {
    union { unsigned short u[8]; s8v v; } r;
    r.u[0] = f2bf(a.x); r.u[1] = f2bf(a.y); r.u[2] = f2bf(a.z); r.u[3] = f2bf(a.w);
    r.u[4] = f2bf(b.x); r.u[5] = f2bf(b.y); r.u[6] = f2bf(b.z); r.u[7] = f2bf(b.w);
    return r.v;
}

// Kernel 1: z = h @ W_fc^T via MFMA bf16; writes zb (bf16) + aux epilogue.
__global__ __launch_bounds__(256) void k_gemm(
    const float* __restrict__ h, const float* __restrict__ Wfc,
    const float* __restrict__ a_attn, const float* __restrict__ w_row,
    __hip_bfloat16* __restrict__ zb, float* __restrict__ aux)
{
    __shared__ __align__(16) unsigned short zs[64][72];  // 144 B rows (16B-aligned)
    __shared__ float vec[4][68];

    int t = threadIdx.x, lane = t & 63, wave = t >> 6;
    int g = lane >> 4, c = lane & 15;
    size_t rowbase = (size_t)blockIdx.x * 64;

    {   // stage the 4 reduction vectors for the aux epilogue
        int i = t & 63, ty = t >> 6;
        vec[ty][i] = (ty == 0) ? a_attn[i]
                   : (ty == 1) ? w_row[i]
                   : (ty == 2) ? w_row[64 + i]
                               : a_attn[64 + i];
    }

    // A fragments: m = c (lane&15), k = kt*32 + g*8 + j
    const float* hrow = h + (rowbase + (size_t)wave * 16 + c) * INF;
    s8v afr[4];
#pragma unroll
    for (int kt = 0; kt < 4; ++kt) {
        const float* p = hrow + kt * 32 + g * 8;
        afr[kt] = pack8(*(const float4*)p, *(const float4*)(p + 4));
    }
    // B fragments: n = nt*16 + c, same k mapping (symmetric with A)
    f32x4 acc[4];
#pragma unroll
    for (int nt = 0; nt < 4; ++nt) {
        acc[nt] = (f32x4){0.f, 0.f, 0.f, 0.f};
        const float* wrow = Wfc + (size_t)(nt * 16 + c) * INF;
#pragma unroll
        for (int kt = 0; kt < 4; ++kt) {
            const float* p = wrow + kt * 32 + g * 8;
            s8v bfr = pack8(*(const float4*)p, *(const float4*)(p + 4));
            acc[nt] = __builtin_amdgcn_mfma_f32_16x16x32_bf16(afr[kt], bfr, acc[nt], 0, 0, 0);
        }
    }

    // C/D layout: col = lane&15, row = (lane>>4)*4 + reg
#pragma unroll
    for (int nt = 0; nt < 4; ++nt)
#pragma unroll
        for (int r = 0; r < 4; ++r)
            zs[wave * 16 + g * 4 + r][nt * 16 + c] = f2bf(acc[nt][r]);
    __syncthreads();

    // coalesced stream LDS -> zb (64 rows x 128 B)
#pragma unroll
    for (int it = 0; it < 2; ++it) {
        int f = t + it * 256;          // [0,512): row = f>>3, 16B chunk = f&7
        int row = f >> 3, ch = f & 7;
        uint4 v = *(const uint4*)((const char*)&zs[row][0] + ch * 16);
        *(uint4*)((char*)zb + (rowbase + row) * 128 + ch * 16) = v;
    }

    // aux: thread (row, ty) serial dot over 64 dims
    {
        int row = t >> 2, ty = t & 3;
        const uint4* zr = (const uint4*)&zs[row][0];
        float s = 0.f;
#pragma unroll
        for (int q = 0; q < 8; ++q) {
            uint4 v = zr[q];
            const float* vp = &vec[ty][q * 8];
            s = fmaf(bf2f((unsigned short)(v.x & 0xffff)), vp[0], s);
            s = fmaf(bf2f((unsigned short)(v.x >> 16)),    vp[1], s);
            s = fmaf(bf2f((unsigned short)(v.y & 0xffff)), vp[2], s);
            s = fmaf(bf2f((unsigned short)(v.y >> 16)),    vp[3], s);
            s = fmaf(bf2f((unsigned short)(v.z & 0xffff)), vp[4], s);
            s = fmaf(bf2f((unsigned short)(v.z >> 16)),    vp[5], s);
            s = fmaf(bf2f((unsigned short)(v.w & 0xffff)), vp[6], s);
            s = fmaf(bf2f((unsigned short)(v.w >> 16)),    vp[7], s);
        }
        aux[rowbase * 4 + t] = s;      // coalesced
    }
}

// Kernel 2: softmax + row/col convs + BN sums (direct atomics). Wave = 2 nodes.
// Col gather is L2-blocked: two passes over z halves (4 MB each, fits per-XCD
// L2); out-of-half sources get address remapped into the hot half and alpha=0.
// Out stores are nontemporal so the write stream doesn't evict z from L2.
__global__ __launch_bounds__(256) void k_gat(
    const unsigned short* __restrict__ zb, const float4* __restrict__ aux,
    const int* __restrict__ src_idx, const float* __restrict__ w_col,
    const float* __restrict__ b_row, const float* __restrict__ b_col,
    float* __restrict__ out, float* __restrict__ sums)
{
    __shared__ uint2  s_as[4][2][32];      // (alpha bits, soff bytes)
    __shared__ float  s_wc[2048];          // w_col [32][64]
    __shared__ float4 s_part[4];

    int t = threadIdx.x, lane = t & 63, wave = t >> 6;
    int half = lane >> 5, hl = lane & 31;
    int n = blockIdx.x * 8 + wave * 2 + half;

#pragma unroll
    for (int i = 0; i < 8; ++i) s_wc[t + 256 * i] = w_col[t + 256 * i];

    const float* auxf = (const float*)aux;
    int sk = src_idx[(size_t)n * KK + hl];
    float4 ax = aux[sk];                 // (e_src, zw0, zw1, e_dst) of source
    float ed = auxf[n * 4 + 3];          // e_dst of this node
    float e = ax.x + ed;
    e = e > 0.f ? e : 0.01f * e;         // leaky_relu
    float m = e;
#pragma unroll
    for (int s = 16; s; s >>= 1) m = fmaxf(m, __shfl_xor(m, s));   // stays in half
    float p = __expf(e - m);
    float sum = p;
#pragma unroll
    for (int s = 16; s; s >>= 1) sum += __shfl_xor(sum, s);
    float alpha = p / sum;
    s_as[wave][half][hl] = make_uint2(__float_as_uint(alpha), (unsigned int)sk * 128u);
    float t1 = alpha * ax.z;
    float tn = __shfl_down(t1, 1);       // hl=31 result unused
    float rowv = fmaf(alpha, ax.y, tn) + b_row[0];
    float rs = 0.f, rss = 0.f;
    if (hl < 31) {
        __builtin_nontemporal_store(rowv, &out[(size_t)n * OW + hl]);
        rs = rowv; rss = rowv * rowv;
    }
    __syncthreads();

    const char* zbase = (const char*)zb;
    const uint2* pas = &s_as[wave][half][0];
    unsigned int dof = (unsigned int)hl * 4u;   // this lane's d-pair byte offset

    float acc0 = 0.f, acc1 = 0.f;
#pragma unroll
    for (int pass = 0; pass < 2; ++pass) {
        unsigned int base = pass ? 4194304u : 0u;   // 4 MB half base
#pragma unroll
        for (int kk = 0; kk < 32; ++kk) {
            uint2 av = pas[kk];
            // remap out-of-half sources into the hot half (keeps load in L2)
            unsigned int so = (av.y & 0x3FFFFFu) + base;
            float al = ((av.y >> 22) == (unsigned)pass) ? __uint_as_float(av.x) : 0.f;
            unsigned int zv = *(const unsigned int*)(zbase + (size_t)(so + dof));
            float2 wcp = *(const float2*)&s_wc[kk * 64 + hl * 2];
            union { unsigned int u; float f; } lo, hi;
            lo.u = zv << 16;               // d = 2*hl
            hi.u = zv & 0xffff0000u;       // d = 2*hl+1
            acc0 = fmaf(al * wcp.x, lo.f, acc0);
            acc1 = fmaf(al * wcp.y, hi.f, acc1);
        }
    }
    float bc = b_col[0];
    float colv0 = acc0 + bc, colv1 = acc1 + bc;
    __builtin_nontemporal_store(colv0, &out[(size_t)n * OW + 31 + 2 * hl]);
    __builtin_nontemporal_store(colv1, &out[(size_t)n * OW + 32 + 2 * hl]);

    // BN partial sums -> one atomicAdd set per block
    float cs = colv0 + colv1, css = colv0 * colv0 + colv1 * colv1;
#pragma unroll
    for (int s = 32; s; s >>= 1) {
        rs  += __shfl_xor(rs, s);
        rss += __shfl_xor(rss, s);
        cs  += __shfl_xor(cs, s);
        css += __shfl_xor(css, s);
    }
    if (lane == 0) s_part[wave] = make_float4(rs, rss, cs, css);
    __syncthreads();
    if (t == 0) {
        float4 p0 = s_part[0], p1 = s_part[1], p2 = s_part[2], p3 = s_part[3];
        atomicAdd(&sums[0], p0.x + p1.x + p2.x + p3.x);
        atomicAdd(&sums[1], p0.y + p1.y + p2.y + p3.y);
        atomicAdd(&sums[2], p0.z + p1.z + p2.z + p3.z);
        atomicAdd(&sums[3], p0.w + p1.w + p2.w + p3.w);
    }
}

// Kernel 3: BN scale/bias (computed per block from sums) + ReLU, float4/thread
__global__ __launch_bounds__(256) void k_apply(
    float* __restrict__ out, const float* __restrict__ sums, int N, int total4)
{
    float nrow = (float)N * 31.0f, ncol = (float)N * 64.0f;
    float mr = sums[0] / nrow, vr = sums[1] / nrow - mr * mr;
    float mc = sums[2] / ncol, vc = sums[3] / ncol - mc * mc;
    float sr = sums[4] * __frsqrt_rn(vr + 1e-5f);
    float br = sums[5] - mr * sr;
    float sc = sums[6] * __frsqrt_rn(vc + 1e-5f);
    float bc = sums[7] - mc * sc;

    int idx = blockIdx.x * 256 + threadIdx.x;
    int stride = gridDim.x * 256;
    for (; idx < total4; idx += stride) {
        int i = idx * 4;
        float4 x = *(float4*)(out + i);
        int c = i % OW;
        float r[4] = {x.x, x.y, x.z, x.w};
#pragma unroll
        for (int j = 0; j < 4; ++j) {
            int cj = c + j; if (cj >= OW) cj -= OW;
            float y = (cj < 31) ? fmaf(r[j], sr, br) : fmaf(r[j], sc, bc);
            r[j] = fmaxf(y, 0.0f);
        }
        *(float4*)(out + i) = make_float4(r[0], r[1], r[2], r[3]);
    }
}

// Tiny helper: stage BN affine params (g/beta) next to the atomic sums so
// k_apply needs a single pointer (launched before k_gat; no dependency).
__global__ void k_prep(const float* g_row, const float* beta_row,
                       const float* g_col, const float* beta_col,
                       float* sums)
{
    if (threadIdx.x == 0) {
        sums[4] = g_row[0];
        sums[5] = beta_row[0];
        sums[6] = g_col[0];
        sums[7] = beta_col[0];
    }
}

extern "C" void kernel_launch(void* const* d_in, const int* in_sizes, int n_in,
                              void* d_out, int out_size, void* d_ws, size_t ws_size,
                              hipStream_t stream) {
    const float* h        = (const float*)d_in[0];
    const float* Wfc      = (const float*)d_in[1];
    const float* a_attn   = (const float*)d_in[2];
    const float* w_row    = (const float*)d_in[3];
    const float* b_row    = (const float*)d_in[4];
    const float* w_col    = (const float*)d_in[5];
    const float* b_col    = (const float*)d_in[6];
    const float* g_row    = (const float*)d_in[7];
    const float* beta_row = (const float*)d_in[8];
    const float* g_col    = (const float*)d_in[9];
    const float* beta_col = (const float*)d_in[10];
    const int*   src_idx  = (const int*)d_in[11];

    int N = in_sizes[0] / INF;      // 65536
    float* out = (float*)d_out;

    // workspace layout
    __hip_bfloat16* zb = (__hip_bfloat16*)d_ws;                      // 8 MB
    float* aux  = (float*)((char*)d_ws + (size_t)N * DD * 2);        // 1 MB
    float* sums = aux + (size_t)N * 4;                               // 8 f32

    hipMemsetAsync(sums, 0, 4 * sizeof(float), stream);              // zero atomics
    k_prep <<<1, 64, 0, stream>>>(g_row, beta_row, g_col, beta_col, sums);
    k_gemm <<<N / 64, 256, 0, stream>>>(h, Wfc, a_attn, w_row, zb, aux);
    k_gat  <<<N / 8,  256, 0, stream>>>((const unsigned short*)zb, (const float4*)aux,
                                        src_idx, w_col, b_row, b_col, out, sums);
    int total4 = (N * OW) / 4;
    k_apply<<<2048,   256, 0, stream>>>(out, sums, N, total4);
}

// Round 9
// 548.967 us; speedup vs baseline: 1.0162x; 1.0162x over previous
//
#include <hip/hip_runtime.h>
#include <hip/hip_bf16.h>

#define KK 32
#define INF 128
#define DD 64
#define OW 95   // 31 (row) + 64 (col)

typedef __attribute__((ext_vector_type(8))) short s8v;    // 8 bf16 (4 VGPR)
typedef __attribute__((ext_vector_type(4))) float f32x4;  // MFMA accumulator

__device__ __forceinline__ float bf2f(unsigned short u) {
    union { unsigned int i; float f; } cv; cv.i = (unsigned int)u << 16; return cv.f;
}
__device__ __forceinline__ unsigned short f2bf(float f) {
    __hip_bfloat16 hh = __float2bfloat16(f);
    return *reinterpret_cast<unsigned short*>(&hh);
}
__device__ __forceinline__ s8v pack8(float4 a, float4 b) {
    union { unsigned short u[8]; s8v v; } r;
    r.u[0] = f2bf(a.x); r.u[1] = f2bf(a.y); r.u[2] = f2bf(a.z); r.u[3] = f2bf(a.w);
    r.u[4] = f2bf(b.x); r.u[5] = f2bf(b.y); r.u[6] = f2bf(b.z); r.u[7] = f2bf(b.w);
    return r.v;
}

// Kernel 1: z = h @ W_fc^T via MFMA bf16; writes zb (bf16) + aux epilogue.
// Block 0 also zeroes the BN atomic sums and stages g/beta (replaces the
// old memset + k_prep launches; safe because k_gat is stream-ordered after).
__global__ __launch_bounds__(256) void k_gemm(
    const float* __restrict__ h, const float* __restrict__ Wfc,
    const float* __restrict__ a_attn, const float* __restrict__ w_row,
    const float* __restrict__ g_row, const float* __restrict__ beta_row,
    const float* __restrict__ g_col, const float* __restrict__ beta_col,
    __hip_bfloat16* __restrict__ zb, float* __restrict__ aux,
    float* __restrict__ sums)
{
    __shared__ __align__(16) unsigned short zs[64][72];  // 144 B rows (16B-aligned)
    __shared__ float vec[4][68];

    int t = threadIdx.x, lane = t & 63, wave = t >> 6;
    int g = lane >> 4, c = lane & 15;
    size_t rowbase = (size_t)blockIdx.x * 64;

    if (blockIdx.x == 0 && t < 8) {
        float v = 0.f;
        if (t == 4) v = g_row[0];
        else if (t == 5) v = beta_row[0];
        else if (t == 6) v = g_col[0];
        else if (t == 7) v = beta_col[0];
        sums[t] = v;
    }

    {   // stage the 4 reduction vectors for the aux epilogue
        int i = t & 63, ty = t >> 6;
        vec[ty][i] = (ty == 0) ? a_attn[i]
                   : (ty == 1) ? w_row[i]
                   : (ty == 2) ? w_row[64 + i]
                               : a_attn[64 + i];
    }

    // A fragments: m = c (lane&15), k = kt*32 + g*8 + j
    const float* hrow = h + (rowbase + (size_t)wave * 16 + c) * INF;
    s8v afr[4];
#pragma unroll
    for (int kt = 0; kt < 4; ++kt) {
        const float* p = hrow + kt * 32 + g * 8;
        afr[kt] = pack8(*(const float4*)p, *(const float4*)(p + 4));
    }
    // B fragments: n = nt*16 + c, same k mapping (symmetric with A)
    f32x4 acc[4];
#pragma unroll
    for (int nt = 0; nt < 4; ++nt) {
        acc[nt] = (f32x4){0.f, 0.f, 0.f, 0.f};
        const float* wrow = Wfc + (size_t)(nt * 16 + c) * INF;
#pragma unroll
        for (int kt = 0; kt < 4; ++kt) {
            const float* p = wrow + kt * 32 + g * 8;
            s8v bfr = pack8(*(const float4*)p, *(const float4*)(p + 4));
            acc[nt] = __builtin_amdgcn_mfma_f32_16x16x32_bf16(afr[kt], bfr, acc[nt], 0, 0, 0);
        }
    }

    // C/D layout: col = lane&15, row = (lane>>4)*4 + reg
#pragma unroll
    for (int nt = 0; nt < 4; ++nt)
#pragma unroll
        for (int r = 0; r < 4; ++r)
            zs[wave * 16 + g * 4 + r][nt * 16 + c] = f2bf(acc[nt][r]);
    __syncthreads();

    // coalesced stream LDS -> zb (64 rows x 128 B)
#pragma unroll
    for (int it = 0; it < 2; ++it) {
        int f = t + it * 256;          // [0,512): row = f>>3, 16B chunk = f&7
        int row = f >> 3, ch = f & 7;
        uint4 v = *(const uint4*)((const char*)&zs[row][0] + ch * 16);
        *(uint4*)((char*)zb + (rowbase + row) * 128 + ch * 16) = v;
    }

    // aux: thread (row, ty) serial dot over 64 dims
    {
        int row = t >> 2, ty = t & 3;
        const uint4* zr = (const uint4*)&zs[row][0];
        float s = 0.f;
#pragma unroll
        for (int q = 0; q < 8; ++q) {
            uint4 v = zr[q];
            const float* vp = &vec[ty][q * 8];
            s = fmaf(bf2f((unsigned short)(v.x & 0xffff)), vp[0], s);
            s = fmaf(bf2f((unsigned short)(v.x >> 16)),    vp[1], s);
            s = fmaf(bf2f((unsigned short)(v.y & 0xffff)), vp[2], s);
            s = fmaf(bf2f((unsigned short)(v.y >> 16)),    vp[3], s);
            s = fmaf(bf2f((unsigned short)(v.z & 0xffff)), vp[4], s);
            s = fmaf(bf2f((unsigned short)(v.z >> 16)),    vp[5], s);
            s = fmaf(bf2f((unsigned short)(v.w & 0xffff)), vp[6], s);
            s = fmaf(bf2f((unsigned short)(v.w >> 16)),    vp[7], s);
        }
        aux[rowbase * 4 + t] = s;      // coalesced
    }
}

// Kernel 2: softmax + row/col convs + BN sums. Wave = 2 nodes.
// (r4-proven structure: per-iter LDS alpha/soff reads, dword d-pair gathers.)
__global__ __launch_bounds__(256) void k_gat(
    const unsigned short* __restrict__ zb, const float4* __restrict__ aux,
    const int* __restrict__ src_idx, const float* __restrict__ w_col,
    const float* __restrict__ b_row, const float* __restrict__ b_col,
    float* __restrict__ out, float* __restrict__ sums)
{
    __shared__ uint2  s_as[4][2][32];      // (alpha bits, soff bytes)
    __shared__ float  s_wc[2048];          // w_col [32][64]
    __shared__ float4 s_part[4];

    int t = threadIdx.x, lane = t & 63, wave = t >> 6;
    int half = lane >> 5, hl = lane & 31;
    int n = blockIdx.x * 8 + wave * 2 + half;

#pragma unroll
    for (int i = 0; i < 8; ++i) s_wc[t + 256 * i] = w_col[t + 256 * i];

    const float* auxf = (const float*)aux;
    int sk = src_idx[(size_t)n * KK + hl];
    float4 ax = aux[sk];                 // (e_src, zw0, zw1, e_dst) of source
    float ed = auxf[n * 4 + 3];          // e_dst of this node
    float e = ax.x + ed;
    e = e > 0.f ? e : 0.01f * e;         // leaky_relu
    float m = e;
#pragma unroll
    for (int s = 16; s; s >>= 1) m = fmaxf(m, __shfl_xor(m, s));   // stays in half
    float p = __expf(e - m);
    float sum = p;
#pragma unroll
    for (int s = 16; s; s >>= 1) sum += __shfl_xor(sum, s);
    float alpha = p / sum;
    s_as[wave][half][hl] = make_uint2(__float_as_uint(alpha), (unsigned int)sk * 128u);
    float t1 = alpha * ax.z;
    float tn = __shfl_down(t1, 1);       // hl=31 result unused
    float rowv = fmaf(alpha, ax.y, tn) + b_row[0];
    float rs = 0.f, rss = 0.f;
    if (hl < 31) {
        out[(size_t)n * OW + hl] = rowv;
        rs = rowv; rss = rowv * rowv;
    }
    __syncthreads();

    const char* zbase = (const char*)zb;
    const uint2* pas = &s_as[wave][half][0];
    unsigned int dof = (unsigned int)hl * 4u;   // this lane's d-pair byte offset

    float acc0 = 0.f, acc1 = 0.f;
#pragma unroll
    for (int kk = 0; kk < 32; ++kk) {
        uint2 av = pas[kk];
        unsigned int zv = *(const unsigned int*)(zbase + (size_t)(av.y + dof));
        float2 wcp = *(const float2*)&s_wc[kk * 64 + hl * 2];
        float al = __uint_as_float(av.x);
        union { unsigned int u; float f; } lo, hi;
        lo.u = zv << 16;               // d = 2*hl
        hi.u = zv & 0xffff0000u;       // d = 2*hl+1
        acc0 = fmaf(al * wcp.x, lo.f, acc0);
        acc1 = fmaf(al * wcp.y, hi.f, acc1);
    }
    float bc = b_col[0];
    float colv0 = acc0 + bc, colv1 = acc1 + bc;
    out[(size_t)n * OW + 31 + 2 * hl] = colv0;
    out[(size_t)n * OW + 32 + 2 * hl] = colv1;

    // BN partial sums -> one atomicAdd set per block
    float cs = colv0 + colv1, css = colv0 * colv0 + colv1 * colv1;
#pragma unroll
    for (int s = 32; s; s >>= 1) {
        rs  += __shfl_xor(rs, s);
        rss += __shfl_xor(rss, s);
        cs  += __shfl_xor(cs, s);
        css += __shfl_xor(css, s);
    }
    if (lane == 0) s_part[wave] = make_float4(rs, rss, cs, css);
    __syncthreads();
    if (t == 0) {
        float4 p0 = s_part[0], p1 = s_part[1], p2 = s_part[2], p3 = s_part[3];
        atomicAdd(&sums[0], p0.x + p1.x + p2.x + p3.x);
        atomicAdd(&sums[1], p0.y + p1.y + p2.y + p3.y);
        atomicAdd(&sums[2], p0.z + p1.z + p2.z + p3.z);
        atomicAdd(&sums[3], p0.w + p1.w + p2.w + p3.w);
    }
}

// Kernel 3: BN scale/bias (computed per block from sums) + ReLU, float4/thread
__global__ __launch_bounds__(256) void k_apply(
    float* __restrict__ out, const float* __restrict__ sums, int N, int total4)
{
    float nrow = (float)N * 31.0f, ncol = (float)N * 64.0f;
    float mr = sums[0] / nrow, vr = sums[1] / nrow - mr * mr;
    float mc = sums[2] / ncol, vc = sums[3] / ncol - mc * mc;
    float sr = sums[4] * __frsqrt_rn(vr + 1e-5f);
    float br = sums[5] - mr * sr;
    float sc = sums[6] * __frsqrt_rn(vc + 1e-5f);
    float bc = sums[7] - mc * sc;

    int idx = blockIdx.x * 256 + threadIdx.x;
    int stride = gridDim.x * 256;
    for (; idx < total4; idx += stride) {
        int i = idx * 4;
        float4 x = *(float4*)(out + i);
        int c = i % OW;
        float r[4] = {x.x, x.y, x.z, x.w};
#pragma unroll
        for (int j = 0; j < 4; ++j) {
            int cj = c + j; if (cj >= OW) cj -= OW;
            float y = (cj < 31) ? fmaf(r[j], sr, br) : fmaf(r[j], sc, bc);
            r[j] = fmaxf(y, 0.0f);
        }
        *(float4*)(out + i) = make_float4(r[0], r[1], r[2], r[3]);
    }
}

extern "C" void kernel_launch(void* const* d_in, const int* in_sizes, int n_in,
                              void* d_out, int out_size, void* d_ws, size_t ws_size,
                              hipStream_t stream) {
    const float* h        = (const float*)d_in[0];
    const float* Wfc      = (const float*)d_in[1];
    const float* a_attn   = (const float*)d_in[2];
    const float* w_row    = (const float*)d_in[3];
    const float* b_row    = (const float*)d_in[4];
    const float* w_col    = (const float*)d_in[5];
    const float* b_col    = (const float*)d_in[6];
    const float* g_row    = (const float*)d_in[7];
    const float* beta_row = (const float*)d_in[8];
    const float* g_col    = (const float*)d_in[9];
    const float* beta_col = (const float*)d_in[10];
    const int*   src_idx  = (const int*)d_in[11];

    int N = in_sizes[0] / INF;      // 65536
    float* out = (float*)d_out;

    // workspace layout
    __hip_bfloat16* zb = (__hip_bfloat16*)d_ws;                      // 8 MB
    float* aux  = (float*)((char*)d_ws + (size_t)N * DD * 2);        // 1 MB
    float* sums = aux + (size_t)N * 4;                               // 8 f32

    k_gemm <<<N / 64, 256, 0, stream>>>(h, Wfc, a_attn, w_row,
                                        g_row, beta_row, g_col, beta_col,
                                        zb, aux, sums);
    k_gat  <<<N / 8,  256, 0, stream>>>((const unsigned short*)zb, (const float4*)aux,
                                        src_idx, w_col, b_row, b_col, out, sums);
    int total4 = (N * OW) / 4;
    k_apply<<<2048,   256, 0, stream>>>(out, sums, N, total4);
}

// Round 10
// 167.816 us; speedup vs baseline: 3.3242x; 3.2712x over previous
//
#include <hip/hip_runtime.h>
#include <hip/hip_bf16.h>

#define KK 32
#define INF 128
#define DD 64
#define OW 95   // 31 (row) + 64 (col)
#define NSLOT 128

typedef __attribute__((ext_vector_type(8))) short s8v;    // 8 bf16 (4 VGPR)
typedef __attribute__((ext_vector_type(4))) float f32x4;  // MFMA accumulator

__device__ __forceinline__ float bf2f(unsigned short u) {
    union { unsigned int i; float f; } cv; cv.i = (unsigned int)u << 16; return cv.f;
}
__device__ __forceinline__ unsigned short f2bf(float f) {
    __hip_bfloat16 hh = __float2bfloat16(f);
    return *reinterpret_cast<unsigned short*>(&hh);
}
__device__ __forceinline__ s8v pack8(float4 a, float4 b) {
    union { unsigned short u[8]; s8v v; } r;
    r.u[0] = f2bf(a.x); r.u[1] = f2bf(a.y); r.u[2] = f2bf(a.z); r.u[3] = f2bf(a.w);
    r.u[4] = f2bf(b.x); r.u[5] = f2bf(b.y); r.u[6] = f2bf(b.z); r.u[7] = f2bf(b.w);
    return r.v;
}

// Kernel 1: z = h @ W_fc^T via MFMA bf16; writes zb (bf16) + aux epilogue.
__global__ __launch_bounds__(256) void k_gemm(
    const float* __restrict__ h, const float* __restrict__ Wfc,
    const float* __restrict__ a_attn, const float* __restrict__ w_row,
    __hip_bfloat16* __restrict__ zb, float* __restrict__ aux)
{
    __shared__ __align__(16) unsigned short zs[64][72];  // 144 B rows (16B-aligned)
    __shared__ float vec[4][68];

    int t = threadIdx.x, lane = t & 63, wave = t >> 6;
    int g = lane >> 4, c = lane & 15;
    size_t rowbase = (size_t)blockIdx.x * 64;

    {   // stage the 4 reduction vectors for the aux epilogue
        int i = t & 63, ty = t >> 6;
        vec[ty][i] = (ty == 0) ? a_attn[i]
                   : (ty == 1) ? w_row[i]
                   : (ty == 2) ? w_row[64 + i]
                               : a_attn[64 + i];
    }

    // A fragments: m = c (lane&15), k = kt*32 + g*8 + j
    const float* hrow = h + (rowbase + (size_t)wave * 16 + c) * INF;
    s8v afr[4];
#pragma unroll
    for (int kt = 0; kt < 4; ++kt) {
        const float* p = hrow + kt * 32 + g * 8;
        afr[kt] = pack8(*(const float4*)p, *(const float4*)(p + 4));
    }
    // B fragments: n = nt*16 + c, same k mapping (symmetric with A)
    f32x4 acc[4];
#pragma unroll
    for (int nt = 0; nt < 4; ++nt) {
        acc[nt] = (f32x4){0.f, 0.f, 0.f, 0.f};
        const float* wrow = Wfc + (size_t)(nt * 16 + c) * INF;
#pragma unroll
        for (int kt = 0; kt < 4; ++kt) {
            const float* p = wrow + kt * 32 + g * 8;
            s8v bfr = pack8(*(const float4*)p, *(const float4*)(p + 4));
            acc[nt] = __builtin_amdgcn_mfma_f32_16x16x32_bf16(afr[kt], bfr, acc[nt], 0, 0, 0);
        }
    }

    // C/D layout: col = lane&15, row = (lane>>4)*4 + reg
#pragma unroll
    for (int nt = 0; nt < 4; ++nt)
#pragma unroll
        for (int r = 0; r < 4; ++r)
            zs[wave * 16 + g * 4 + r][nt * 16 + c] = f2bf(acc[nt][r]);
    __syncthreads();

    // coalesced stream LDS -> zb (64 rows x 128 B)
#pragma unroll
    for (int it = 0; it < 2; ++it) {
        int f = t + it * 256;          // [0,512): row = f>>3, 16B chunk = f&7
        int row = f >> 3, ch = f & 7;
        uint4 v = *(const uint4*)((const char*)&zs[row][0] + ch * 16);
        *(uint4*)((char*)zb + (rowbase + row) * 128 + ch * 16) = v;
    }

    // aux: thread (row, ty) serial dot over 64 dims
    {
        int row = t >> 2, ty = t & 3;
        const uint4* zr = (const uint4*)&zs[row][0];
        float s = 0.f;
#pragma unroll
        for (int q = 0; q < 8; ++q) {
            uint4 v = zr[q];
            const float* vp = &vec[ty][q * 8];
            s = fmaf(bf2f((unsigned short)(v.x & 0xffff)), vp[0], s);
            s = fmaf(bf2f((unsigned short)(v.x >> 16)),    vp[1], s);
            s = fmaf(bf2f((unsigned short)(v.y & 0xffff)), vp[2], s);
            s = fmaf(bf2f((unsigned short)(v.y >> 16)),    vp[3], s);
            s = fmaf(bf2f((unsigned short)(v.z & 0xffff)), vp[4], s);
            s = fmaf(bf2f((unsigned short)(v.z >> 16)),    vp[5], s);
            s = fmaf(bf2f((unsigned short)(v.w & 0xffff)), vp[6], s);
            s = fmaf(bf2f((unsigned short)(v.w >> 16)),    vp[7], s);
        }
        aux[rowbase * 4 + t] = s;      // coalesced
    }
}

// Kernel 2: softmax + row/col convs + BN partials (r4-proven inner structure).
// Epilogue: atomicAdd into 128 slot-sets -> max 64 same-address RMWs per slot.
__global__ __launch_bounds__(256) void k_gat(
    const unsigned short* __restrict__ zb, const float4* __restrict__ aux,
    const int* __restrict__ src_idx, const float* __restrict__ w_col,
    const float* __restrict__ b_row, const float* __restrict__ b_col,
    float* __restrict__ out, float* __restrict__ slots)
{
    __shared__ uint2  s_as[4][2][32];      // (alpha bits, soff bytes)
    __shared__ float  s_wc[2048];          // w_col [32][64]
    __shared__ float4 s_part[8];

    int t = threadIdx.x, lane = t & 63, wave = t >> 6;
    int half = lane >> 5, hl = lane & 31;
    int n = blockIdx.x * 8 + wave * 2 + half;

#pragma unroll
    for (int i = 0; i < 8; ++i) s_wc[t + 256 * i] = w_col[t + 256 * i];

    const float* auxf = (const float*)aux;
    int sk = src_idx[(size_t)n * KK + hl];
    float4 ax = aux[sk];                 // (e_src, zw0, zw1, e_dst) of source
    float ed = auxf[n * 4 + 3];          // e_dst of this node
    float e = ax.x + ed;
    e = e > 0.f ? e : 0.01f * e;         // leaky_relu
    float m = e;
#pragma unroll
    for (int s = 16; s; s >>= 1) m = fmaxf(m, __shfl_xor(m, s));   // stays in half
    float p = __expf(e - m);
    float sum = p;
#pragma unroll
    for (int s = 16; s; s >>= 1) sum += __shfl_xor(sum, s);
    float alpha = p / sum;
    s_as[wave][half][hl] = make_uint2(__float_as_uint(alpha), (unsigned int)sk * 128u);
    float t1 = alpha * ax.z;
    float tn = __shfl_down(t1, 1);       // hl=31 result unused
    float rowv = fmaf(alpha, ax.y, tn) + b_row[0];
    float rs = 0.f, rss = 0.f;
    if (hl < 31) {
        out[(size_t)n * OW + hl] = rowv;
        rs = rowv; rss = rowv * rowv;
    }
    __syncthreads();

    const char* zbase = (const char*)zb;
    const uint2* pas = &s_as[wave][half][0];
    unsigned int dof = (unsigned int)hl * 4u;   // this lane's d-pair byte offset

    float acc0 = 0.f, acc1 = 0.f;
#pragma unroll
    for (int kk = 0; kk < 32; ++kk) {
        uint2 av = pas[kk];
        unsigned int zv = *(const unsigned int*)(zbase + (size_t)(av.y + dof));
        float2 wcp = *(const float2*)&s_wc[kk * 64 + hl * 2];
        float al = __uint_as_float(av.x);
        union { unsigned int u; float f; } lo, hi;
        lo.u = zv << 16;               // d = 2*hl
        hi.u = zv & 0xffff0000u;       // d = 2*hl+1
        acc0 = fmaf(al * wcp.x, lo.f, acc0);
        acc1 = fmaf(al * wcp.y, hi.f, acc1);
    }
    float bc = b_col[0];
    float colv0 = acc0 + bc, colv1 = acc1 + bc;
    out[(size_t)n * OW + 31 + 2 * hl] = colv0;
    out[(size_t)n * OW + 32 + 2 * hl] = colv1;

    // BN partial sums (r4 reduce) -> one atomicAdd set per block into a slot
    float cs = colv0 + colv1, css = colv0 * colv0 + colv1 * colv1;
#pragma unroll
    for (int s = 16; s; s >>= 1) {
        rs  += __shfl_xor(rs, s);
        rss += __shfl_xor(rss, s);
        cs  += __shfl_xor(cs, s);
        css += __shfl_xor(css, s);
    }
    if (hl == 0) s_part[wave * 2 + half] = make_float4(rs, rss, cs, css);
    __syncthreads();
    if (t == 0) {
        float4 a = make_float4(0.f, 0.f, 0.f, 0.f);
#pragma unroll
        for (int i = 0; i < 8; ++i) {
            a.x += s_part[i].x; a.y += s_part[i].y;
            a.z += s_part[i].z; a.w += s_part[i].w;
        }
        float* sl = slots + (size_t)(blockIdx.x & (NSLOT - 1)) * 4;
        atomicAdd(&sl[0], a.x);
        atomicAdd(&sl[1], a.y);
        atomicAdd(&sl[2], a.z);
        atomicAdd(&sl[3], a.w);
    }
}

// Kernel 3: reduce the 128 slots (per-wave, redundant), BN affine + ReLU.
__global__ __launch_bounds__(256) void k_apply(
    float* __restrict__ out, const float* __restrict__ slots,
    const float* __restrict__ g_row, const float* __restrict__ beta_row,
    const float* __restrict__ g_col, const float* __restrict__ beta_col,
    int N, int total4)
{
    int t = threadIdx.x, lane = t & 63;
    const float4* sl4 = (const float4*)slots;
    float4 a = sl4[lane], b = sl4[lane + 64];
    float s0 = a.x + b.x, s1 = a.y + b.y, s2 = a.z + b.z, s3 = a.w + b.w;
#pragma unroll
    for (int s = 32; s; s >>= 1) {
        s0 += __shfl_xor(s0, s);
        s1 += __shfl_xor(s1, s);
        s2 += __shfl_xor(s2, s);
        s3 += __shfl_xor(s3, s);
    }
    // all lanes now hold the grid totals
    float nrow = (float)N * 31.0f, ncol = (float)N * 64.0f;
    float mr = s0 / nrow, vr = s1 / nrow - mr * mr;
    float mc = s2 / ncol, vc = s3 / ncol - mc * mc;
    float sr = g_row[0] * __frsqrt_rn(vr + 1e-5f);
    float br = beta_row[0] - mr * sr;
    float sc = g_col[0] * __frsqrt_rn(vc + 1e-5f);
    float bc = beta_col[0] - mc * sc;

    int idx = blockIdx.x * 256 + t;
    int stride = gridDim.x * 256;
    for (; idx < total4; idx += stride) {
        int i = idx * 4;
        float4 x = *(float4*)(out + i);
        int c = i % OW;
        float r[4] = {x.x, x.y, x.z, x.w};
#pragma unroll
        for (int j = 0; j < 4; ++j) {
            int cj = c + j; if (cj >= OW) cj -= OW;
            float y = (cj < 31) ? fmaf(r[j], sr, br) : fmaf(r[j], sc, bc);
            r[j] = fmaxf(y, 0.0f);
        }
        *(float4*)(out + i) = make_float4(r[0], r[1], r[2], r[3]);
    }
}

extern "C" void kernel_launch(void* const* d_in, const int* in_sizes, int n_in,
                              void* d_out, int out_size, void* d_ws, size_t ws_size,
                              hipStream_t stream) {
    const float* h        = (const float*)d_in[0];
    const float* Wfc      = (const float*)d_in[1];
    const float* a_attn   = (const float*)d_in[2];
    const float* w_row    = (const float*)d_in[3];
    const float* b_row    = (const float*)d_in[4];
    const float* w_col    = (const float*)d_in[5];
    const float* b_col    = (const float*)d_in[6];
    const float* g_row    = (const float*)d_in[7];
    const float* beta_row = (const float*)d_in[8];
    const float* g_col    = (const float*)d_in[9];
    const float* beta_col = (const float*)d_in[10];
    const int*   src_idx  = (const int*)d_in[11];

    int N = in_sizes[0] / INF;      // 65536
    float* out = (float*)d_out;

    // workspace layout
    __hip_bfloat16* zb = (__hip_bfloat16*)d_ws;                      // 8 MB
    float* aux   = (float*)((char*)d_ws + (size_t)N * DD * 2);       // 1 MB
    float* slots = aux + (size_t)N * 4;                              // 128*4 f32

    hipMemsetAsync(slots, 0, NSLOT * 4 * sizeof(float), stream);
    k_gemm <<<N / 64, 256, 0, stream>>>(h, Wfc, a_attn, w_row, zb, aux);
    k_gat  <<<N / 8,  256, 0, stream>>>((const unsigned short*)zb, (const float4*)aux,
                                        src_idx, w_col, b_row, b_col, out, slots);
    int total4 = (N * OW) / 4;
    k_apply<<<2048,   256, 0, stream>>>(out, slots, g_row, beta_row, g_col, beta_col,
                                        N, total4);
}